// Round 11
// baseline (105.469 us; speedup 1.0000x reference)
//
#include <hip/hip_runtime.h>

// (B,H,W,C) = (16,512,512,3) float32. 4 warp ops.
// out concat order: 0:(frame1,f01) 1:(frame0,f10) 2:(frame0,ft0) 3:(frame1,ft1)
#define HH 512
#define WW 512
#define NPIX (16 * HH * WW)
#define IMG_DW (HH * WW * 3)     // dwords per image
#define ROWD_G (WW * 3)          // global image row stride in dwords

#define TSX   32                 // output tile width
#define TSY   16                 // output tile height
#define APRX  12                 // x apron
#define APRY  10                 // y apron
#define LWX   (TSX + 2 * APRX)   // 56: staged region width (px)
#define LWY   (TSY + 2 * APRY)   // 36: staged region height (rows)
#define ROWD  (LWX * 3)          // 168 payload dwords per region row
#define LSTR  172                // padded LDS row stride (16B chunk-aligned: 172%4==0)
#define LDSDW (LWY * LSTR)       // 6192 dwords = 24,768 B per buffer
#define NCHUNK (LDSDW / 4)       // 1548 16B chunks = 6*256 + 12
#define NTILE 4                  // x-adjacent tiles pipelined per block

typedef float fv4 __attribute__((ext_vector_type(4)));
typedef float fv2 __attribute__((ext_vector_type(2)));
typedef fv4 fv4u __attribute__((aligned(4)));
typedef fv2 fv2u __attribute__((aligned(4)));

// Issue the async HBM->LDS staging for one tile's apron region (no VGPR payload).
__device__ __forceinline__ void stage(const float* __restrict__ imgb,
                                      float* __restrict__ ldsbase,
                                      int AX0, int AY0, int tid, unsigned wid)
{
    int row = (tid * 4) / LSTR;          // magic-mul once
    int rd  = (tid * 4) - row * LSTR;
#pragma unroll
    for (int it = 0; it < 7; ++it) {
        if (it < 6 || tid < (NCHUNK - 6 * 256)) {   // 12 tail chunks
            const int gy = min(max(AY0 + row, 0), HH - 1);
            int idx = gy * ROWD_G + AX0 * 3 + rd;
            idx = min(max(idx, 0), IMG_DW - 4);     // fault-safety only
            __builtin_amdgcn_global_load_lds(
                (const __attribute__((address_space(1))) void*)(imgb + idx),
                (__attribute__((address_space(3))) void*)(ldsbase + it * 1024 + wid * 256),
                16, 0, 0);
        }
        // advance dword index by 1024: 1024 = 5*172 + 164
        row += 5; rd += 164;
        if (rd >= LSTR) { rd -= LSTR; ++row; }
    }
}

__device__ __forceinline__ void sample(const float* __restrict__ imgb,
                                       const float* __restrict__ s,
                                       int AX0, int AY0,
                                       float qy, float qx, float* __restrict__ r)
{
    float fy = floorf(qy); fy = fminf(fmaxf(fy, 0.0f), (float)(HH - 2));
    float fx = floorf(qx); fx = fminf(fmaxf(fx, 0.0f), (float)(WW - 2));
    const float ay = fminf(fmaxf(qy - fy, 0.0f), 1.0f);
    const float ax = fminf(fmaxf(qx - fx, 0.0f), 1.0f);
    const int y0 = (int)fy, x0 = (int)fx;
    const int yl = y0 - AY0, xl = x0 - AX0;
    if ((unsigned)yl < (unsigned)(LWY - 1) && (unsigned)xl < (unsigned)(LWX - 1)) {
        // LDS path: AoS rows; adjacent-pair dwords -> ds_read2_b32
        const float* t  = s + yl * LSTR + 3 * xl;
        const float* bo = t + LSTR;
#pragma unroll
        for (int c = 0; c < 3; ++c) {
            const float tl = t[c],  tr = t[c + 3];
            const float bl = bo[c], br = bo[c + 3];
            const float top = tl + ax * (tr - tl);
            const float bot = bl + ax * (br - bl);
            r[c] = top + ay * (bot - top);
        }
    } else {
        // rare global fallback (|flow| beyond apron): exact same math
        const float* t  = imgb + ((size_t)y0 * WW + x0) * 3;
        const float* bo = t + WW * 3;
        const fv4u t4 = *(const fv4u*)t;  const fv2u t2 = *(const fv2u*)(t + 4);
        const fv4u b4 = *(const fv4u*)bo; const fv2u b2 = *(const fv2u*)(bo + 4);
        const float tv[6] = {t4.x, t4.y, t4.z, t4.w, t2.x, t2.y};
        const float bv[6] = {b4.x, b4.y, b4.z, b4.w, b2.x, b2.y};
#pragma unroll
        for (int c = 0; c < 3; ++c) {
            const float top = tv[c] + ax * (tv[c + 3] - tv[c]);
            const float bot = bv[c] + ax * (bv[c + 3] - bv[c]);
            r[c] = top + ay * (bot - top);
        }
    }
}

__global__ __launch_bounds__(256) void warp_dbuf_kernel(
    const float* __restrict__ frame0, const float* __restrict__ frame1,
    const float* __restrict__ f01, const float* __restrict__ f10,
    const float* __restrict__ ft0, const float* __restrict__ ft1,
    float* __restrict__ out)
{
    __shared__ float lds[2 * LDSDW];   // 49,536 B -> 3 blocks/CU

    // 4096 block-units (each = 4 x-adjacent tiles). Bijective XCD chunking:
    // XCD k gets 512 contiguous units = 4 whole (fg,b) images (fits 4MB L2);
    // consecutive units walk x then y, so apron overlap stays L2-hot.
    const unsigned bid = blockIdx.x;
    const unsigned u   = (bid & 7u) * 512u + (bid >> 3);

    const int ux    = (int)(u & 3u);         // 4 tile-quads per row
    const int ty    = (int)((u >> 2) & 31u); // 32 tile-rows per image
    const unsigned img_b = u >> 7;           // 0..31
    const int b  = (int)(img_b & 15u);
    const int fg = (int)(img_b >> 4);        // 0: frame0 ops{1,2}, 1: frame1 ops{0,3}

    const int txb = ux * NTILE;              // first tile x-index
    const int Y0  = ty * TSY;
    const int AY0 = Y0 - APRY;

    const float* img   = fg ? frame1 : frame0;
    const float* flowA = fg ? f01 : f10;
    const float* flowB = fg ? ft1 : ft0;
    const size_t opA   = fg ? 0 : 1;
    const size_t opB   = fg ? 3 : 2;
    const float* imgb  = img + (size_t)b * IMG_DW;

    const int tid = (int)threadIdx.x;
    const unsigned wid = __builtin_amdgcn_readfirstlane((unsigned)tid >> 6);
    const int lx = (tid & 15) * 2;           // 16 threads x 2 px cover 32-px row
    const int ly = tid >> 4;                 // 16 rows
    const int y  = Y0 + ly;
    const size_t rowBase = ((size_t)b * HH + y) * WW;

    // Prologue: stage tile 0 into buf0; prefetch tile 0 flows.
    stage(imgb, lds, txb * TSX - APRX, AY0, tid, wid);
    fv4 fa = __builtin_nontemporal_load((const fv4*)(flowA + (rowBase + txb * TSX + lx) * 2));
    fv4 fc = __builtin_nontemporal_load((const fv4*)(flowB + (rowBase + txb * TSX + lx) * 2));

#pragma unroll
    for (int t = 0; t < NTILE; ++t) {
        const int X0  = (txb + t) * TSX;
        const int AX0 = X0 - APRX;
        const int x   = X0 + lx;
        const size_t pixIn = rowBase + x;

        // Barrier drains this wave's outstanding glds (tile t complete) and
        // guarantees buf[(t+1)&1] (= tile t-1's buffer) is no longer read.
        __syncthreads();

        fv4 fa_n = fa, fc_n = fc;
        if (t < NTILE - 1) {
            // Issue tile t+1 staging now; its latency hides under tile t's
            // compute below (drained only at the NEXT barrier).
            stage(imgb, lds + ((t + 1) & 1) * LDSDW, AX0 + TSX, AY0, tid, wid);
            fa_n = __builtin_nontemporal_load((const fv4*)(flowA + (pixIn + TSX) * 2));
            fc_n = __builtin_nontemporal_load((const fv4*)(flowB + (pixIn + TSX) * 2));
        }

        const float* sbuf = lds + (t & 1) * LDSDW;
        float* oA = out + (opA * NPIX + pixIn) * 3;
        float* oB = out + (opB * NPIX + pixIn) * 3;

        // Op A: 2 samples, store immediately.
        {
            float res[6];
            sample(imgb, sbuf, AX0, AY0, (float)y - fa.x, (float)x       - fa.y, res);
            sample(imgb, sbuf, AX0, AY0, (float)y - fa.z, (float)(x + 1) - fa.w, res + 3);
            fv2 v0s = {res[0], res[1]};
            fv2 v1s = {res[2], res[3]};
            fv2 v2s = {res[4], res[5]};
            __builtin_nontemporal_store(v0s, (fv2*)oA);
            __builtin_nontemporal_store(v1s, (fv2*)oA + 1);
            __builtin_nontemporal_store(v2s, (fv2*)oA + 2);
        }
        // Op B
        {
            float res[6];
            sample(imgb, sbuf, AX0, AY0, (float)y - fc.x, (float)x       - fc.y, res);
            sample(imgb, sbuf, AX0, AY0, (float)y - fc.z, (float)(x + 1) - fc.w, res + 3);
            fv2 v0s = {res[0], res[1]};
            fv2 v1s = {res[2], res[3]};
            fv2 v2s = {res[4], res[5]};
            __builtin_nontemporal_store(v0s, (fv2*)oB);
            __builtin_nontemporal_store(v1s, (fv2*)oB + 1);
            __builtin_nontemporal_store(v2s, (fv2*)oB + 2);
        }

        fa = fa_n; fc = fc_n;
    }
}

extern "C" void kernel_launch(void* const* d_in, const int* in_sizes, int n_in,
                              void* d_out, int out_size, void* d_ws, size_t ws_size,
                              hipStream_t stream) {
    const float* frame0 = (const float*)d_in[0];
    const float* frame1 = (const float*)d_in[1];
    const float* f01    = (const float*)d_in[2];
    const float* f10    = (const float*)d_in[3];
    const float* ft0    = (const float*)d_in[4];
    const float* ft1    = (const float*)d_in[5];
    float* out = (float*)d_out;

    // 2 fg * 16 b * 32 ty * 4 ux = 4096 blocks of 256 threads (4 tiles each).
    hipLaunchKernelGGL(warp_dbuf_kernel, dim3(4096), dim3(256), 0, stream,
                       frame0, frame1, f01, f10, ft0, ft1, out);
}

// Round 12
// 97.518 us; speedup vs baseline: 1.0815x; 1.0815x over previous
//
#include <hip/hip_runtime.h>

// (B,H,W,C) = (16,512,512,3) float32. 4 warp ops.
// out concat order: 0:(frame1,f01) 1:(frame0,f10) 2:(frame0,ft0) 3:(frame1,ft1)
#define HH 512
#define WW 512
#define NPIX (16 * HH * WW)
#define IMG_DW (HH * WW * 3)     // dwords per image
#define ROWD_G (WW * 3)          // global image row stride in dwords

#define TSX   32                 // output tile width
#define TSY   16                 // output tile height
#define APRX  12                 // x apron
#define APRY  12                 // y apron (R9 rate; R10's 10 raised fallback 5x)
#define LWX   (TSX + 2 * APRX)   // 56: staged region width (px)
#define LWY   (TSY + 2 * APRY)   // 40: staged region height (rows)
#define LSTR  (LWX * 3)          // 168: unpadded row stride (16B chunk-aligned: 168%4==0)
#define LDSDW (LWY * LSTR)       // 6720 dwords = 26,880 B -> 6 blocks/CU (75% ceiling)
#define NCHUNK (LDSDW / 4)       // 1680 16B chunks = 6*256 + 144

typedef float fv4 __attribute__((ext_vector_type(4)));
typedef float fv2 __attribute__((ext_vector_type(2)));
typedef fv4 fv4u __attribute__((aligned(4)));
typedef fv2 fv2u __attribute__((aligned(4)));

__device__ __forceinline__ void sample(const float* __restrict__ imgb,
                                       const float* __restrict__ s,
                                       int AX0, int AY0,
                                       float qy, float qx, float* __restrict__ r)
{
    float fy = floorf(qy); fy = fminf(fmaxf(fy, 0.0f), (float)(HH - 2));
    float fx = floorf(qx); fx = fminf(fmaxf(fx, 0.0f), (float)(WW - 2));
    const float ay = fminf(fmaxf(qy - fy, 0.0f), 1.0f);
    const float ax = fminf(fmaxf(qx - fx, 0.0f), 1.0f);
    const int y0 = (int)fy, x0 = (int)fx;
    const int yl = y0 - AY0, xl = x0 - AX0;
    if ((unsigned)yl < (unsigned)(LWY - 1) && (unsigned)xl < (unsigned)(LWX - 1)) {
        // LDS path: AoS rows; one base addr, 6x ds_read2_b32 with imm offsets
        // (c, c+3, LSTR+c, LSTR+c+3 all <= 171 < 256 dword-imm range).
        const float* t  = s + yl * LSTR + 3 * xl;
        const float* bo = t + LSTR;
#pragma unroll
        for (int c = 0; c < 3; ++c) {
            const float tl = t[c],  tr = t[c + 3];
            const float bl = bo[c], br = bo[c + 3];
            const float top = tl + ax * (tr - tl);
            const float bot = bl + ax * (br - bl);
            r[c] = top + ay * (bot - top);
        }
    } else {
        // rare global fallback (|flow| beyond apron): exact same math
        const float* t  = imgb + ((size_t)y0 * WW + x0) * 3;
        const float* bo = t + WW * 3;
        const fv4u t4 = *(const fv4u*)t;  const fv2u t2 = *(const fv2u*)(t + 4);
        const fv4u b4 = *(const fv4u*)bo; const fv2u b2 = *(const fv2u*)(bo + 4);
        const float tv[6] = {t4.x, t4.y, t4.z, t4.w, t2.x, t2.y};
        const float bv[6] = {b4.x, b4.y, b4.z, b4.w, b2.x, b2.y};
#pragma unroll
        for (int c = 0; c < 3; ++c) {
            const float top = tv[c] + ax * (tv[c + 3] - tv[c]);
            const float bot = bv[c] + ax * (bv[c + 3] - bv[c]);
            r[c] = top + ay * (bot - top);
        }
    }
}

__global__ __launch_bounds__(256) void warp_glds6b_kernel(
    const float* __restrict__ frame0, const float* __restrict__ frame1,
    const float* __restrict__ f01, const float* __restrict__ f10,
    const float* __restrict__ ft0, const float* __restrict__ ft1,
    float* __restrict__ out)
{
    __shared__ float lds[LDSDW];   // 26,880 B -> 6 blocks/CU (24 waves, 75%)

    // 16384 blocks; bijective XCD chunking: XCD k gets 2048 contiguous units
    // = 4 whole (fg,b) images; consecutive units walk one image row-by-row,
    // so apron re-reads between adjacent tiles stay L2-resident.
    const unsigned bid = blockIdx.x;
    const unsigned v   = (bid & 7u) * 2048u + (bid >> 3);

    const unsigned tile  = v & 511u;   // 16 x 32 tiles per image
    const unsigned img_b = v >> 9;     // 0..31
    const int b  = (int)(img_b & 15u);
    const int fg = (int)(img_b >> 4);  // 0: frame0 ops{1,2}, 1: frame1 ops{0,3}

    const int tx = (int)(tile & 15u);
    const int ty = (int)(tile >> 4);
    const int X0 = tx * TSX, Y0 = ty * TSY;
    const int AX0 = X0 - APRX, AY0 = Y0 - APRY;

    const float* img   = fg ? frame1 : frame0;
    const float* flowA = fg ? f01 : f10;
    const float* flowB = fg ? ft1 : ft0;
    const size_t opA   = fg ? 0 : 1;
    const size_t opB   = fg ? 3 : 2;

    const float* imgb = img + (size_t)b * IMG_DW;

    const int tid = (int)threadIdx.x;
    const int lx = (tid & 15) * 2;     // 16 threads x 2 px cover 32 px row
    const int ly = tid >> 4;           // 16 rows
    const int x = X0 + lx, y = Y0 + ly;
    const size_t pixIn = ((size_t)b * HH + y) * WW + x;

    // Flow loads (2 px -> one 16B load per op); consumed after the barrier.
    const fv4 a = __builtin_nontemporal_load((const fv4*)(flowA + pixIn * 2));
    const fv4 c = __builtin_nontemporal_load((const fv4*)(flowB + pixIn * 2));

    // ---- Stage apron region HBM -> LDS via global_load_lds (async, 0 VGPR).
    // 1680 16B chunks; thread tid handles chunk it*256+tid. LDS dest is
    // wave-uniform base + lane*16 (HW contract); LSTR%4==0 and rows are
    // unpadded so every chunk is pure payload within one region row.
    // Out-of-image apron cells are never read (bilinear clip); source index
    // clamp is fault-safety only.
    {
        const unsigned wid = __builtin_amdgcn_readfirstlane((unsigned)tid >> 6);
        int D   = tid * 4;             // LDS dword index of this thread's chunk
        int row = D / LSTR;            // magic-mul, once
        int rd  = D - row * LSTR;
#pragma unroll
        for (int it = 0; it < 7; ++it) {
            if (it < 6 || tid < (NCHUNK - 6 * 256)) {   // 144 tail chunks
                const int gy = min(max(AY0 + row, 0), HH - 1);
                int idx = gy * ROWD_G + AX0 * 3 + rd;
                idx = min(max(idx, 0), IMG_DW - 4);
                const float* src = imgb + idx;
                float* dst = (float*)lds + it * 1024 + wid * 256;
                __builtin_amdgcn_global_load_lds(
                    (const __attribute__((address_space(1))) void*)src,
                    (__attribute__((address_space(3))) void*)dst, 16, 0, 0);
            }
            // advance D by 1024 dwords: 1024 = 6*168 + 16
            row += 6; rd += 16;
            if (rd >= LSTR) { rd -= LSTR; ++row; }
        }
    }
    __syncthreads();   // compiler drains vmcnt before s_barrier

    float* oA = out + (opA * NPIX + pixIn) * 3;
    float* oB = out + (opB * NPIX + pixIn) * 3;

    // Op A: 2 samples, store immediately (short live-range).
    {
        float res[6];
        sample(imgb, lds, AX0, AY0, (float)y - a.x, (float)x       - a.y, res);
        sample(imgb, lds, AX0, AY0, (float)y - a.z, (float)(x + 1) - a.w, res + 3);
        fv2 v0s = {res[0], res[1]};
        fv2 v1s = {res[2], res[3]};
        fv2 v2s = {res[4], res[5]};
        __builtin_nontemporal_store(v0s, (fv2*)oA);
        __builtin_nontemporal_store(v1s, (fv2*)oA + 1);
        __builtin_nontemporal_store(v2s, (fv2*)oA + 2);
    }
    // Op B
    {
        float res[6];
        sample(imgb, lds, AX0, AY0, (float)y - c.x, (float)x       - c.y, res);
        sample(imgb, lds, AX0, AY0, (float)y - c.z, (float)(x + 1) - c.w, res + 3);
        fv2 v0s = {res[0], res[1]};
        fv2 v1s = {res[2], res[3]};
        fv2 v2s = {res[4], res[5]};
        __builtin_nontemporal_store(v0s, (fv2*)oB);
        __builtin_nontemporal_store(v1s, (fv2*)oB + 1);
        __builtin_nontemporal_store(v2s, (fv2*)oB + 2);
    }
}

extern "C" void kernel_launch(void* const* d_in, const int* in_sizes, int n_in,
                              void* d_out, int out_size, void* d_ws, size_t ws_size,
                              hipStream_t stream) {
    const float* frame0 = (const float*)d_in[0];
    const float* frame1 = (const float*)d_in[1];
    const float* f01    = (const float*)d_in[2];
    const float* f10    = (const float*)d_in[3];
    const float* ft0    = (const float*)d_in[4];
    const float* ft1    = (const float*)d_in[5];
    float* out = (float*)d_out;

    // 2 frame-groups * 16 b * 512 tiles = 16384 blocks of 256 threads.
    hipLaunchKernelGGL(warp_glds6b_kernel, dim3(16384), dim3(256), 0, stream,
                       frame0, frame1, f01, f10, ft0, ft1, out);
}